// Round 1
// baseline (789.983 us; speedup 1.0000x reference)
//
#include <hip/hip_runtime.h>
#include <hip/hip_bf16.h>

typedef __bf16 bf16x8 __attribute__((ext_vector_type(8)));
typedef __bf16 bf16x4 __attribute__((ext_vector_type(4)));
typedef float f32x4 __attribute__((ext_vector_type(4)));

#define S_LEN 2048
#define HID 2560
#define NH 32
#define NKV 8
#define HD 128
#define QSZ 4096      // NH*HD
#define KVSZ 1024     // NKV*HD
#define QKV_N 6144    // QSZ + 2*KVSZ
#define SCALE_Q 0.08838834764831845f  // 128^-0.5
#define LOG2_THETA 13.287712379549449f // log2(10000)

// ---------------- f32 -> bf16 cast ----------------
__global__ void castk(const float* __restrict__ in, __bf16* __restrict__ out, int n4) {
  int i = blockIdx.x * blockDim.x + threadIdx.x;
  int stride = gridDim.x * blockDim.x;
  for (; i < n4; i += stride) {
    float4 v = ((const float4*)in)[i];
    bf16x4 o;
    o[0] = (__bf16)v.x; o[1] = (__bf16)v.y; o[2] = (__bf16)v.z; o[3] = (__bf16)v.w;
    ((bf16x4*)out)[i] = o;
  }
}

// ---------------- async global->LDS helper ----------------
__device__ __forceinline__ void gload16(const void* g, void* l) {
  __builtin_amdgcn_global_load_lds((const __attribute__((address_space(1))) void*)g,
                                   (__attribute__((address_space(3))) void*)l, 16, 0, 0);
}

// ---------------- bf16 GEMM: C[M][N] = A[M][K] * B[N][K]^T, fp32 out ----------------
// m97 structure: 128x128 tile, BK=32, global_load_lds(16), 4 waves 2x2, 16 MFMA/K-step.
__global__ __launch_bounds__(256, 2) void gemm_bt(
    const __bf16* __restrict__ A, const __bf16* __restrict__ B, float* __restrict__ C,
    int M, int N, int K) {
  __shared__ __attribute__((aligned(16))) __bf16 lta[128 * 32];
  __shared__ __attribute__((aligned(16))) __bf16 ltb[128 * 32];
  const int t = threadIdx.x, w = t >> 6, l = t & 63;
  const int bn = blockIdx.x, bm = blockIdx.y;
  const int wr = w >> 1, wc = w & 1;
  const int lg = l >> 4, li = l & 15;

  f32x4 acc[4][4];
#pragma unroll
  for (int i = 0; i < 4; ++i)
#pragma unroll
    for (int j = 0; j < 4; ++j) acc[i][j] = (f32x4){0.f, 0.f, 0.f, 0.f};

  const int nkt = K >> 5;
  const int c0 = w * 2, c1 = w * 2 + 1;
  const int row0 = c0 * 16 + (l >> 2), row1 = c1 * 16 + (l >> 2);
  const int cole = (l & 3) * 8;
  const __bf16* ga = A + (size_t)(bm * 128) * K + cole;
  const __bf16* gb = B + (size_t)(bn * 128) * K + cole;

  for (int kt = 0; kt < nkt; ++kt) {
    const size_t ko = (size_t)kt * 32;
    gload16(ga + (size_t)row0 * K + ko, &lta[c0 * 512]);
    gload16(gb + (size_t)row0 * K + ko, &ltb[c0 * 512]);
    gload16(ga + (size_t)row1 * K + ko, &lta[c1 * 512]);
    gload16(gb + (size_t)row1 * K + ko, &ltb[c1 * 512]);
    __syncthreads();
    bf16x8 af[4], bfr[4];
#pragma unroll
    for (int f = 0; f < 4; ++f) {
      af[f]  = *(const bf16x8*)&lta[(wr * 64 + f * 16 + li) * 32 + lg * 8];
      bfr[f] = *(const bf16x8*)&ltb[(wc * 64 + f * 16 + li) * 32 + lg * 8];
    }
#pragma unroll
    for (int fm = 0; fm < 4; ++fm)
#pragma unroll
      for (int fn = 0; fn < 4; ++fn)
        acc[fm][fn] = __builtin_amdgcn_mfma_f32_16x16x32_bf16(af[fm], bfr[fn], acc[fm][fn], 0, 0, 0);
    __syncthreads();
  }

  float* cp = C + (size_t)(bm * 128 + wr * 64 + lg * 4) * N + bn * 128 + wc * 64 + li;
#pragma unroll
  for (int fm = 0; fm < 4; ++fm)
#pragma unroll
    for (int fn = 0; fn < 4; ++fn)
#pragma unroll
      for (int r = 0; r < 4; ++r)
        cp[(size_t)(fm * 16 + r) * N + fn * 16] = acc[fm][fn][r];
}

// ---------------- fused RMSNorm + RoPE, write bf16 q/k ----------------
// grid (2048, 40): y<32 -> q head, else k head. 64 threads, lane d handles (d, d+64).
__global__ __launch_bounds__(64) void norm_rope(
    const float* __restrict__ qkv, const int* __restrict__ positions,
    const float* __restrict__ qw, const float* __restrict__ kw,
    __bf16* __restrict__ q_bf, __bf16* __restrict__ k_bf) {
  const int s = blockIdx.x, hh = blockIdx.y, l = threadIdx.x;
  const float* row;
  const float* wgt;
  __bf16* outp;
  float scale;
  if (hh < NH) {
    row = qkv + (size_t)s * QKV_N + hh * HD;
    wgt = qw;
    outp = q_bf + ((size_t)s * NH + hh) * HD;
    scale = SCALE_Q;
  } else {
    row = qkv + (size_t)s * QKV_N + QSZ + (hh - NH) * HD;
    wgt = kw;
    outp = k_bf + ((size_t)s * NKV + (hh - NH)) * HD;
    scale = 1.0f;
  }
  float x1 = row[l], x2 = row[l + 64];
  float ss = x1 * x1 + x2 * x2;
#pragma unroll
  for (int off = 32; off; off >>= 1) ss += __shfl_xor(ss, off, 64);
  float rs = rsqrtf(ss * (1.0f / 128.0f) + 1e-6f);
  float n1 = x1 * rs * wgt[l], n2 = x2 * rs * wgt[l + 64];
  float ang = (float)positions[s] * exp2f((float)l * (-LOG2_THETA / 64.0f));
  float sn, cs;
  sincosf(ang, &sn, &cs);
  outp[l]      = (__bf16)((n1 * cs - n2 * sn) * scale);
  outp[l + 64] = (__bf16)((n2 * cs + n1 * sn) * scale);
}

// ---------------- V transpose: qkv f32 -> vt_bf[hk][d][s] ----------------
// grid (64, 8): 32 s-rows x one kv head per block, 256 threads.
__global__ __launch_bounds__(256) void v_prep(const float* __restrict__ qkv, __bf16* __restrict__ vt) {
  const int s0 = blockIdx.x * 32, hk = blockIdx.y;
  __shared__ float lv[32][129];
  const int t = threadIdx.x;
  {
    const int s = t >> 3, dseg = (t & 7) * 16;
    const float* src = qkv + (size_t)(s0 + s) * QKV_N + (QSZ + KVSZ) + hk * HD + dseg;
#pragma unroll
    for (int j = 0; j < 4; ++j) {
      float4 v = *(const float4*)(src + j * 4);
      lv[s][dseg + j * 4 + 0] = v.x;
      lv[s][dseg + j * 4 + 1] = v.y;
      lv[s][dseg + j * 4 + 2] = v.z;
      lv[s][dseg + j * 4 + 3] = v.w;
    }
  }
  __syncthreads();
  {
    const int d = t >> 1, sh = (t & 1) * 16;
    bf16x8 a, b;
#pragma unroll
    for (int j = 0; j < 8; ++j) {
      a[j] = (__bf16)lv[sh + j][d];
      b[j] = (__bf16)lv[sh + 8 + j][d];
    }
    __bf16* dst = vt + ((size_t)hk * HD + d) * S_LEN + s0 + sh;
    *(bf16x8*)dst = a;
    *(bf16x8*)(dst + 8) = b;
  }
}

// ---------------- flash attention (bf16 MFMA, fp32 softmax) ----------------
// grid (32 qtiles, 32 heads), 256 threads = 4 independent waves, 16 q-rows each.
__global__ __launch_bounds__(256, 2) void flash_attn(
    const __bf16* __restrict__ q_bf, const __bf16* __restrict__ k_bf,
    const __bf16* __restrict__ vt_bf, __bf16* __restrict__ o_bf) {
  const int t = threadIdx.x;
  const int w = t >> 6, l = t & 63;
  const int qtile = blockIdx.x, h = blockIdx.y;
  const int hk = h >> 2;
  const int q0 = qtile * 64 + w * 16;
  const int lg = l >> 4, li = l & 15;

  __shared__ __attribute__((aligned(16))) __bf16 p_lds[4][16][40];

  // Q fragments (A-layout: row=li, k=lg*8+j), SCALE pre-folded
  bf16x8 aq[4];
  {
    const __bf16* qp = q_bf + ((size_t)(q0 + li) * NH + h) * HD + lg * 8;
#pragma unroll
    for (int c = 0; c < 4; ++c) aq[c] = *(const bf16x8*)(qp + c * 32);
  }

  float m_r[4], l_r[4];
  f32x4 o_acc[8];
#pragma unroll
  for (int r = 0; r < 4; ++r) { m_r[r] = -1e30f; l_r[r] = 0.f; }
#pragma unroll
  for (int fd = 0; fd < 8; ++fd) o_acc[fd] = (f32x4){0.f, 0.f, 0.f, 0.f};

  const int nkt = ((q0 + 15) >> 5) + 1;
  for (int kb = 0; kb < nkt; ++kb) {
    // QK^T: S[16 q][32 keys] as two 16x16 fragments
    f32x4 s0 = {0.f, 0.f, 0.f, 0.f}, s1 = {0.f, 0.f, 0.f, 0.f};
    const __bf16* kp = k_bf + ((size_t)(kb * 32 + li) * NKV + hk) * HD + lg * 8;
#pragma unroll
    for (int c = 0; c < 4; ++c) {
      bf16x8 b0 = *(const bf16x8*)(kp + c * 32);
      bf16x8 b1 = *(const bf16x8*)(kp + (size_t)16 * NKV * HD + c * 32);
      s0 = __builtin_amdgcn_mfma_f32_16x16x32_bf16(aq[c], b0, s0, 0, 0, 0);
      s1 = __builtin_amdgcn_mfma_f32_16x16x32_bf16(aq[c], b1, s1, 0, 0, 0);
    }
    const int key0 = kb * 32 + li;
    // online softmax per q-row (D layout: row=lg*4+r, col=li)
#pragma unroll
    for (int r = 0; r < 4; ++r) {
      const int q = q0 + lg * 4 + r;
      float v0 = (key0      <= q) ? s0[r] : -1e30f;
      float v1 = (key0 + 16 <= q) ? s1[r] : -1e30f;
      float tm = fmaxf(v0, v1);
#pragma unroll
      for (int off = 8; off; off >>= 1) tm = fmaxf(tm, __shfl_xor(tm, off, 16));
      float mn = fmaxf(m_r[r], tm);
      float sc = __expf(m_r[r] - mn);
      float e0 = __expf(v0 - mn), e1 = __expf(v1 - mn);
      float ps = e0 + e1;
#pragma unroll
      for (int off = 8; off; off >>= 1) ps += __shfl_xor(ps, off, 16);
      l_r[r] = l_r[r] * sc + ps;
      m_r[r] = mn;
#pragma unroll
      for (int fd = 0; fd < 8; ++fd) o_acc[fd][r] *= sc;
      p_lds[w][lg * 4 + r][li]      = (__bf16)e0;
      p_lds[w][lg * 4 + r][li + 16] = (__bf16)e1;
    }
    // P relayout via LDS -> A-fragment (row=li, key=lg*8+j) — same-wave, no barrier
    bf16x8 pa = *(const bf16x8*)&p_lds[w][li][lg * 8];
    // PV: B from vt (B[k=key][n=d]) — contiguous 16B along keys
    const __bf16* vp = vt_bf + ((size_t)hk * HD + li) * S_LEN + kb * 32 + lg * 8;
#pragma unroll
    for (int fd = 0; fd < 8; ++fd) {
      bf16x8 bv = *(const bf16x8*)(vp + (size_t)fd * 16 * S_LEN);
      o_acc[fd] = __builtin_amdgcn_mfma_f32_16x16x32_bf16(pa, bv, o_acc[fd], 0, 0, 0);
    }
  }

  // normalize + write o_bf[s][h*128+d]
  const size_t obase = (size_t)(q0 + lg * 4) * QSZ + (size_t)h * HD + li;
#pragma unroll
  for (int r = 0; r < 4; ++r) {
    float inv = 1.0f / l_r[r];
#pragma unroll
    for (int fd = 0; fd < 8; ++fd)
      o_bf[obase + (size_t)r * QSZ + fd * 16] = (__bf16)(o_acc[fd][r] * inv);
  }
}

// ---------------- launch ----------------
extern "C" void kernel_launch(void* const* d_in, const int* in_sizes, int n_in,
                              void* d_out, int out_size, void* d_ws, size_t ws_size,
                              hipStream_t stream) {
  const int*   positions = (const int*)d_in[0];
  const float* hidden    = (const float*)d_in[1];
  const float* w_qkv     = (const float*)d_in[2];
  const float* w_o       = (const float*)d_in[3];
  const float* q_norm_w  = (const float*)d_in[4];
  const float* k_norm_w  = (const float*)d_in[5];
  float* out = (float*)d_out;

  char* p = (char*)d_ws;
  float*  qkv = (float*)p;   p += (size_t)S_LEN * QKV_N * 4;   // 50.3 MB
  __bf16* hs  = (__bf16*)p;  p += (size_t)S_LEN * HID * 2;     // 10.5 MB
  __bf16* wq  = (__bf16*)p;  p += (size_t)QKV_N * HID * 2;     // 31.5 MB
  __bf16* wo  = (__bf16*)p;  p += (size_t)HID * QSZ * 2;       // 21.0 MB
  __bf16* qb  = (__bf16*)p;  p += (size_t)S_LEN * QSZ * 2;     // 16.8 MB
  __bf16* kb  = (__bf16*)p;  p += (size_t)S_LEN * KVSZ * 2;    //  4.2 MB
  __bf16* vt  = (__bf16*)p;  p += (size_t)NKV * HD * S_LEN * 2;//  4.2 MB
  __bf16* ob  = (__bf16*)p;  p += (size_t)S_LEN * QSZ * 2;     // 16.8 MB

  castk<<<2048, 256, 0, stream>>>(hidden, hs, S_LEN * HID / 4);
  castk<<<2048, 256, 0, stream>>>(w_qkv, wq, QKV_N * HID / 4);
  castk<<<2048, 256, 0, stream>>>(w_o, wo, HID * QSZ / 4);

  gemm_bt<<<dim3(QKV_N / 128, S_LEN / 128), 256, 0, stream>>>(hs, wq, qkv, S_LEN, QKV_N, HID);

  norm_rope<<<dim3(S_LEN, NH + NKV), 64, 0, stream>>>(qkv, positions, q_norm_w, k_norm_w, qb, kb);
  v_prep<<<dim3(S_LEN / 32, NKV), 256, 0, stream>>>(qkv, vt);

  flash_attn<<<dim3(S_LEN / 64, NH), 256, 0, stream>>>(qb, kb, vt, ob);

  gemm_bt<<<dim3(HID / 128, S_LEN / 128), 256, 0, stream>>>(ob, wo, out, S_LEN, HID, QSZ);
}